// Round 5
// baseline (626.564 us; speedup 1.0000x reference)
//
#include <hip/hip_runtime.h>
#include <hip/hip_bf16.h>

#define N_NODES 30000
#define N_REL   8
#define N_EDGES 131072
#define FEAT    512
#define KTOT    4608   // 8*512 + 512
#define CAP     32

typedef __attribute__((ext_vector_type(8))) __bf16 v8bf;
typedef __attribute__((ext_vector_type(4))) __bf16 v4bf;
typedef __attribute__((ext_vector_type(4))) float  v4f;
typedef __attribute__((ext_vector_type(8))) unsigned short u16x8;

// ---------- async global->LDS (16B per lane, wave-uniform LDS base) ----------
static __device__ __forceinline__ void load_lds16(const void* g, void* l) {
  __builtin_amdgcn_global_load_lds(
      (const __attribute__((address_space(1))) void*)g,
      (__attribute__((address_space(3))) void*)l, 16, 0, 0);
}

// ---------- fp32 -> bf16 convert of x ----------
__global__ void k_convert_x(const float* __restrict__ x, __bf16* __restrict__ xbf) {
  int i = blockIdx.x * 256 + threadIdx.x;           // each handles 4 elems
  float4 v = ((const float4*)x)[i];
  v4bf o;
  o[0] = (__bf16)v.x; o[1] = (__bf16)v.y; o[2] = (__bf16)v.z; o[3] = (__bf16)v.w;
  ((v4bf*)xbf)[i] = o;
}

// ---------- build W_t[n][k] = W_cat[k][n] (bf16) ----------
__global__ void k_transpose_w(const float* __restrict__ w, const float* __restrict__ lw,
                              __bf16* __restrict__ Wt) {
  __shared__ float t[32][33];
  int k0 = blockIdx.x * 32;      // 144 blocks
  int n0 = blockIdx.y * 32;      // 16 blocks
  int tx = threadIdx.x & 31, ty = threadIdx.x >> 5;   // 32 x 8
  #pragma unroll
  for (int q = 0; q < 4; ++q) {
    int k = k0 + ty + q * 8, n = n0 + tx;
    float v = (k < 4096) ? w[(size_t)k * 512 + n] : lw[(size_t)(k - 4096) * 512 + n];
    t[ty + q * 8][tx] = v;
  }
  __syncthreads();
  #pragma unroll
  for (int q = 0; q < 4; ++q) {
    int n = n0 + ty + q * 8, k = k0 + tx;
    Wt[(size_t)n * KTOT + k] = (__bf16)t[tx][ty + q * 8];
  }
}

// ---------- bucket build: 4 edges/thread, independent atomics for MLP ----------
__global__ void k_count(const int* __restrict__ src, const int* __restrict__ dst,
                        int* __restrict__ cnt, unsigned short* __restrict__ slots) {
  int t = blockIdx.x * 256 + threadIdx.x;           // 262144 threads
  int e0 = t * 4;
  int4 s4 = *(const int4*)(src + e0);
  int4 d4 = *(const int4*)(dst + e0);
  int ss[4] = {s4.x, s4.y, s4.z, s4.w};
  int dd[4] = {d4.x, d4.y, d4.z, d4.w};
  int b[4], p[4];
  #pragma unroll
  for (int j = 0; j < 4; ++j) {
    int rel = (e0 + j) >> 17;
    b[j] = rel * N_NODES + dd[j];
    p[j] = atomicAdd(&cnt[b[j]], 1);
  }
  #pragma unroll
  for (int j = 0; j < 4; ++j)
    if (p[j] < CAP) slots[(size_t)b[j] * CAP + p[j]] = (unsigned short)ss[j];
}

// ---------- aggregation, L2-resident feature-phase version ----------
// phase = blockIdx.y selects 64 feats; per-phase x-slice = 30000 x 128 B = 3.84 MB
// -> fits each XCD's 4 MB L2. 8-lane group per bucket (128 B row reads),
// per-lane predicated 8-deep load batches. Gather re-reads run at L2 rate.
__global__ __launch_bounds__(256)
void k_aggregate(const __bf16* __restrict__ xbf, const int* __restrict__ cnt,
                 const unsigned short* __restrict__ slots,
                 __bf16* __restrict__ out, int nBuckets) {
  int gid = blockIdx.x * 256 + threadIdx.x;
  int b = gid >> 3;                                 // bucket per 8-lane group
  if (b >= nBuckets) return;
  int fo = blockIdx.y * 64 + (gid & 7) * 8;         // element offset within row
  const unsigned short* sl = slots + (size_t)b * CAP;
  u16x8 qs[4];                                      // full slot line, issued up front
  qs[0] = *(const u16x8*)(sl);
  qs[1] = *(const u16x8*)(sl + 8);
  qs[2] = *(const u16x8*)(sl + 16);
  qs[3] = *(const u16x8*)(sl + 24);
  int c = cnt[b];
  int cc = c < CAP ? c : CAP;
  const __bf16* xb = xbf + fo;
  float acc[8] = {0.f,0.f,0.f,0.f,0.f,0.f,0.f,0.f};
  #pragma unroll
  for (int g = 0; g < 4; ++g) {
    if (__any(cc > g * 8)) {
      v8bf r[8];
      #pragma unroll
      for (int j = 0; j < 8; ++j)
        if (cc > g * 8 + j) r[j] = *(const v8bf*)(xb + (size_t)qs[g][j] * FEAT);
      #pragma unroll
      for (int j = 0; j < 8; ++j)
        if (cc > g * 8 + j) {
          #pragma unroll
          for (int t = 0; t < 8; ++t) acc[t] += (float)r[j][t];
        }
    }
  }
  float scale = 1.0f / (float)(c > 1 ? c : 1);
  v8bf o;
  #pragma unroll
  for (int t = 0; t < 8; ++t) o[t] = (__bf16)(acc[t] * scale);
  *(v8bf*)(out + (size_t)b * FEAT + fo) = o;
}

// ---------- GEMM: 128x128 tile, mfma 16x16x32 bf16, XOR-swizzled LDS ----------
template <bool ACCUM, bool FINAL>
__global__ __launch_bounds__(256, 4)
void k_gemm(const __bf16* __restrict__ A, size_t slabStride,
            const __bf16* __restrict__ Wt, int wtStride, int kTiles,
            const float* __restrict__ bias, float* __restrict__ C) {
  __shared__ __bf16 As[128 * 64];
  __shared__ __bf16 Bs[128 * 64];

  const int tid  = threadIdx.x;
  const int wave = tid >> 6;
  const int lane = tid & 63;
  const int lr = lane >> 3, lc = lane & 7;     // staging: row-in-chunk, 16B slot
  const int gcs = (lc ^ lr) * 8;               // swizzled global chunk (elem offset)
  const int quad = lane >> 4, l15 = lane & 15; // mfma lane decomposition
  const int wRow = wave >> 1, wCol = wave & 1;

  const int panel = blockIdx.x >> 5;
  const int w32   = blockIdx.x & 31;
  const int mtile = panel * 8 + (w32 >> 2);
  const int ntile = w32 & 3;
  if (mtile >= (N_NODES + 127) / 128) return;  // uniform whole-block exit
  const int mBase = mtile * 128;
  const int nBase = ntile * 128;

  v4f acc[4][4];
  #pragma unroll
  for (int i = 0; i < 4; ++i)
    #pragma unroll
    for (int j = 0; j < 4; ++j) acc[i][j] = (v4f){0.f, 0.f, 0.f, 0.f};

  for (int kt = 0; kt < kTiles; ++kt) {
    const int kk = kt * 64;
    const __bf16* aT = A + (size_t)(kk >> 9) * slabStride + (kk & 511);
    #pragma unroll
    for (int t = 0; t < 4; ++t) {
      int chunk = wave * 4 + t;                 // 8 rows x 64 cols per chunk
      int row = mBase + chunk * 8 + lr;
      if (row > N_NODES - 1) row = N_NODES - 1; // clamp; masked at store
      load_lds16(aT + (size_t)row * FEAT + gcs, As + chunk * 512);
      int n = nBase + chunk * 8 + lr;
      load_lds16(Wt + (size_t)n * wtStride + kk + gcs, Bs + chunk * 512);
    }
    __syncthreads();
    #pragma unroll
    for (int ks = 0; ks < 2; ++ks) {
      const int q = ks * 4 + quad;              // 16B chunk wanted this phase
      v8bf af[4], bfr[4];
      #pragma unroll
      for (int mi = 0; mi < 4; ++mi) {
        int m = wRow * 64 + mi * 16 + l15;
        af[mi] = *(const v8bf*)(As + m * 64 + ((q ^ (m & 7)) * 8));
      }
      #pragma unroll
      for (int ni = 0; ni < 4; ++ni) {
        int n = wCol * 64 + ni * 16 + l15;
        bfr[ni] = *(const v8bf*)(Bs + n * 64 + ((q ^ (n & 7)) * 8));
      }
      #pragma unroll
      for (int mi = 0; mi < 4; ++mi)
        #pragma unroll
        for (int ni = 0; ni < 4; ++ni)
          acc[mi][ni] = __builtin_amdgcn_mfma_f32_16x16x32_bf16(af[mi], bfr[ni], acc[mi][ni], 0, 0, 0);
    }
    __syncthreads();
  }

  // epilogue: D row = quad*4+r, col = l15 within each 16x16 tile
  #pragma unroll
  for (int ni = 0; ni < 4; ++ni) {
    int col = nBase + wCol * 64 + ni * 16 + l15;
    float bv = FINAL ? bias[col] : 0.0f;
    #pragma unroll
    for (int mi = 0; mi < 4; ++mi) {
      int row0 = mBase + wRow * 64 + mi * 16 + quad * 4;
      #pragma unroll
      for (int r = 0; r < 4; ++r) {
        int row = row0 + r;
        if (row < N_NODES) {
          size_t idx = (size_t)row * FEAT + col;
          float v = acc[mi][ni][r];
          if (ACCUM) v += C[idx];
          if (FINAL) { v += bv; v = fmaxf(v, 0.0f); }
          C[idx] = v;
        }
      }
    }
  }
}

extern "C" void kernel_launch(void* const* d_in, const int* in_sizes, int n_in,
                              void* d_out, int out_size, void* d_ws, size_t ws_size,
                              hipStream_t stream) {
  const float* x    = (const float*)d_in[0];
  const float* w    = (const float*)d_in[1];
  const float* lw   = (const float*)d_in[2];
  const float* bias = (const float*)d_in[3];
  const int*   src  = (const int*)d_in[4];
  const int*   dst  = (const int*)d_in[5];
  float* out = (float*)d_out;

  char* ws = (char*)d_ws;
  const size_t SLAB  = (size_t)N_NODES * FEAT;              // elems per slab
  const size_t slabB = SLAB * 2;                            // 30.72 MB
  const size_t wtB   = (size_t)FEAT * KTOT * 2;             // 4.72 MB
  const size_t cntB  = (size_t)N_REL * N_NODES * 4;         // 0.96 MB
  const size_t slotB = (size_t)N_REL * N_NODES * CAP * 2;   // 15.36 MB (u16)
  const size_t fixedB = wtB + cntB + slotB;                 // 21.04 MB

  __bf16*         Wt     = (__bf16*)ws;
  int*            cnt    = (int*)(ws + wtB);
  unsigned short* slots  = (unsigned short*)(ws + wtB + cntB);
  __bf16*         slabs  = (__bf16*)(ws + fixedB);          // 16B-aligned

  int nSlab = (int)((ws_size - fixedB) / slabB);            // total slots incl. x slot
  if (nSlab > 9) nSlab = 9;
  int g = nSlab - 1;                                        // agg slabs per GEMM pass
  if (g > 8) g = 8;
  if (g < 1) g = 1;
  __bf16* xbf = slabs + (size_t)g * SLAB;                   // last slot = x (bf16)

  const int nConvBlocks  = (N_NODES * FEAT / 4) / 256;      // 15000
  const int nCountBlocks = (N_REL * N_EDGES / 4) / 256;     // 1024

  hipMemsetAsync(cnt, 0, cntB, stream);
  k_convert_x<<<nConvBlocks, 256, 0, stream>>>(x, xbf);
  k_transpose_w<<<dim3(KTOT / 32, FEAT / 32), 256, 0, stream>>>(w, lw, Wt);
  k_count<<<nCountBlocks, 256, 0, stream>>>(src, dst, cnt, slots);

  const int nMtiles  = (N_NODES + 127) / 128;               // 235
  const int gemmGrid = ((nMtiles + 7) / 8) * 32;            // 30 panels x 32 = 960

  if (g == 8) {
    // single fused GEMM: agg slabs 0..7, x at slot 8 (contiguous) -> K = 4608
    int nB = N_REL * N_NODES;                               // 240000 buckets
    k_aggregate<<<dim3((nB * 8 + 255) / 256, 8), 256, 0, stream>>>(
        xbf, cnt, slots, slabs, nB);
    k_gemm<false, true><<<gemmGrid, 256, 0, stream>>>(slabs, SLAB, Wt, KTOT,
                                                      KTOT / 64, bias, out);
  } else {
    for (int r0 = 0; r0 < N_REL; r0 += g) {
      int gc2 = (N_REL - r0) < g ? (N_REL - r0) : g;
      int nB = gc2 * N_NODES;
      k_aggregate<<<dim3((nB * 8 + 255) / 256, 8), 256, 0, stream>>>(
          xbf, cnt + r0 * N_NODES, slots + (size_t)r0 * N_NODES * CAP,
          slabs, nB);
      if (r0 == 0)
        k_gemm<false, false><<<gemmGrid, 256, 0, stream>>>(
            slabs, SLAB, Wt + r0 * 512, KTOT, gc2 * 8, bias, out);
      else
        k_gemm<true, false><<<gemmGrid, 256, 0, stream>>>(
            slabs, SLAB, Wt + r0 * 512, KTOT, gc2 * 8, bias, out);
    }
    k_gemm<true, true><<<gemmGrid, 256, 0, stream>>>(xbf, SLAB, Wt + 4096, KTOT,
                                                     8, bias, out);
  }
}

// Round 6
// 612.785 us; speedup vs baseline: 1.0225x; 1.0225x over previous
//
#include <hip/hip_runtime.h>
#include <hip/hip_bf16.h>

#define N_NODES 30000
#define N_REL   8
#define N_EDGES 131072
#define FEAT    512
#define KTOT    4608   // 8*512 + 512
#define CAP     32

typedef __attribute__((ext_vector_type(8))) __bf16 v8bf;
typedef __attribute__((ext_vector_type(4))) __bf16 v4bf;
typedef __attribute__((ext_vector_type(4))) float  v4f;
typedef __attribute__((ext_vector_type(8))) unsigned short u16x8;

// ---------- async global->LDS (16B per lane, wave-uniform LDS base) ----------
static __device__ __forceinline__ void load_lds16(const void* g, void* l) {
  __builtin_amdgcn_global_load_lds(
      (const __attribute__((address_space(1))) void*)g,
      (__attribute__((address_space(3))) void*)l, 16, 0, 0);
}

// ---------- fused prep: convert x, transpose W, build buckets ----------
// blocks [0,15000): fp32->bf16 convert of x
// blocks [15000,17304): W transpose (144 x 16 tiles flattened)
// blocks [17304,17816): edge bucket insert, 8 edges/thread
#define CONV_BLOCKS 15000
#define TR_BLOCKS   2304
#define CNT_BLOCKS  512
__global__ __launch_bounds__(256)
void k_prep(const float* __restrict__ x, const float* __restrict__ w,
            const float* __restrict__ lw, const int* __restrict__ src,
            const int* __restrict__ dst, __bf16* __restrict__ xbf,
            __bf16* __restrict__ Wt, int* __restrict__ cnt,
            unsigned short* __restrict__ slots) {
  __shared__ float t[32][33];
  const int b = blockIdx.x, tid = threadIdx.x;
  if (b < CONV_BLOCKS) {
    int i = b * 256 + tid;                          // 4 elems each
    float4 v = ((const float4*)x)[i];
    v4bf o;
    o[0] = (__bf16)v.x; o[1] = (__bf16)v.y; o[2] = (__bf16)v.z; o[3] = (__bf16)v.w;
    ((v4bf*)xbf)[i] = o;
  } else if (b < CONV_BLOCKS + TR_BLOCKS) {
    int tb = b - CONV_BLOCKS;
    int k0 = (tb % 144) * 32, n0 = (tb / 144) * 32;
    int tx = tid & 31, ty = tid >> 5;               // 32 x 8
    #pragma unroll
    for (int q = 0; q < 4; ++q) {
      int k = k0 + ty + q * 8, n = n0 + tx;
      float v = (k < 4096) ? w[(size_t)k * 512 + n] : lw[(size_t)(k - 4096) * 512 + n];
      t[ty + q * 8][tx] = v;
    }
    __syncthreads();
    #pragma unroll
    for (int q = 0; q < 4; ++q) {
      int n = n0 + ty + q * 8, k = k0 + tx;
      Wt[(size_t)n * KTOT + k] = (__bf16)t[tx][ty + q * 8];
    }
  } else {
    int tl = (b - CONV_BLOCKS - TR_BLOCKS) * 256 + tid;
    int e0 = tl * 8;                                // 8 edges, all same rel
    int rel = e0 >> 17;
    int4 sa = *(const int4*)(src + e0), sb = *(const int4*)(src + e0 + 4);
    int4 da = *(const int4*)(dst + e0), db = *(const int4*)(dst + e0 + 4);
    int ss[8] = {sa.x, sa.y, sa.z, sa.w, sb.x, sb.y, sb.z, sb.w};
    int dd[8] = {da.x, da.y, da.z, da.w, db.x, db.y, db.z, db.w};
    int bb[8], pp[8];
    #pragma unroll
    for (int j = 0; j < 8; ++j) {
      bb[j] = rel * N_NODES + dd[j];
      pp[j] = atomicAdd(&cnt[bb[j]], 1);
    }
    #pragma unroll
    for (int j = 0; j < 8; ++j)
      if (pp[j] < CAP) slots[(size_t)bb[j] * CAP + pp[j]] = (unsigned short)ss[j];
  }
}

// ---------- aggregation: one wave/bucket; full-line slot prefetch + 8-deep
// wave-uniform-branch load groups ----------
__global__ __launch_bounds__(256)
void k_aggregate(const __bf16* __restrict__ xbf, const int* __restrict__ cnt,
                 const unsigned short* __restrict__ slots,
                 __bf16* __restrict__ out, int nBuckets) {
  int w = (blockIdx.x * blockDim.x + threadIdx.x) >> 6;
  int lane = threadIdx.x & 63;
  if (w >= nBuckets) return;
  const unsigned short* sl = slots + (size_t)w * CAP;
  u16x8 qs[4];                                      // one 64B line, issued up front
  qs[0] = *(const u16x8*)(sl);
  qs[1] = *(const u16x8*)(sl + 8);
  qs[2] = *(const u16x8*)(sl + 16);
  qs[3] = *(const u16x8*)(sl + 24);
  int c = cnt[w];
  int cc = c < CAP ? c : CAP;
  const __bf16* xb = xbf + (size_t)lane * 8;
  float acc[8] = {0.f,0.f,0.f,0.f,0.f,0.f,0.f,0.f};
  #pragma unroll
  for (int g = 0; g < 4; ++g) {
    if (cc > g * 8) {                               // wave-uniform branch
      int m = cc - g * 8;
      v8bf r[8];
      #pragma unroll
      for (int j = 0; j < 8; ++j)
        if (m > j) r[j] = *(const v8bf*)(xb + (size_t)qs[g][j] * FEAT);
      #pragma unroll
      for (int j = 0; j < 8; ++j)
        if (m > j) {
          #pragma unroll
          for (int t = 0; t < 8; ++t) acc[t] += (float)r[j][t];
        }
    }
  }
  float scale = 1.0f / (float)(c > 1 ? c : 1);
  v8bf o;
  #pragma unroll
  for (int t = 0; t < 8; ++t) o[t] = (__bf16)(acc[t] * scale);
  *(v8bf*)(out + (size_t)w * FEAT + lane * 8) = o;
}

// ---------- GEMM: 128x128 tile, mfma 16x16x32 bf16, XOR-swizzled LDS ----------
template <bool ACCUM, bool FINAL>
__global__ __launch_bounds__(256, 4)
void k_gemm(const __bf16* __restrict__ A, size_t slabStride,
            const __bf16* __restrict__ Wt, int wtStride, int kTiles,
            const float* __restrict__ bias, float* __restrict__ C) {
  __shared__ __bf16 As[128 * 64];
  __shared__ __bf16 Bs[128 * 64];

  const int tid  = threadIdx.x;
  const int wave = tid >> 6;
  const int lane = tid & 63;
  const int lr = lane >> 3, lc = lane & 7;     // staging: row-in-chunk, 16B slot
  const int gcs = (lc ^ lr) * 8;               // swizzled global chunk (elem offset)
  const int quad = lane >> 4, l15 = lane & 15; // mfma lane decomposition
  const int wRow = wave >> 1, wCol = wave & 1;

  const int panel = blockIdx.x >> 5;
  const int w32   = blockIdx.x & 31;
  const int mtile = panel * 8 + (w32 >> 2);
  const int ntile = w32 & 3;
  if (mtile >= (N_NODES + 127) / 128) return;  // uniform whole-block exit
  const int mBase = mtile * 128;
  const int nBase = ntile * 128;

  v4f acc[4][4];
  #pragma unroll
  for (int i = 0; i < 4; ++i)
    #pragma unroll
    for (int j = 0; j < 4; ++j) acc[i][j] = (v4f){0.f, 0.f, 0.f, 0.f};

  for (int kt = 0; kt < kTiles; ++kt) {
    const int kk = kt * 64;
    const __bf16* aT = A + (size_t)(kk >> 9) * slabStride + (kk & 511);
    #pragma unroll
    for (int t = 0; t < 4; ++t) {
      int chunk = wave * 4 + t;                 // 8 rows x 64 cols per chunk
      int row = mBase + chunk * 8 + lr;
      if (row > N_NODES - 1) row = N_NODES - 1; // clamp; masked at store
      load_lds16(aT + (size_t)row * FEAT + gcs, As + chunk * 512);
      int n = nBase + chunk * 8 + lr;
      load_lds16(Wt + (size_t)n * wtStride + kk + gcs, Bs + chunk * 512);
    }
    __syncthreads();
    #pragma unroll
    for (int ks = 0; ks < 2; ++ks) {
      const int q = ks * 4 + quad;              // 16B chunk wanted this phase
      v8bf af[4], bfr[4];
      #pragma unroll
      for (int mi = 0; mi < 4; ++mi) {
        int m = wRow * 64 + mi * 16 + l15;
        af[mi] = *(const v8bf*)(As + m * 64 + ((q ^ (m & 7)) * 8));
      }
      #pragma unroll
      for (int ni = 0; ni < 4; ++ni) {
        int n = wCol * 64 + ni * 16 + l15;
        bfr[ni] = *(const v8bf*)(Bs + n * 64 + ((q ^ (n & 7)) * 8));
      }
      #pragma unroll
      for (int mi = 0; mi < 4; ++mi)
        #pragma unroll
        for (int ni = 0; ni < 4; ++ni)
          acc[mi][ni] = __builtin_amdgcn_mfma_f32_16x16x32_bf16(af[mi], bfr[ni], acc[mi][ni], 0, 0, 0);
    }
    __syncthreads();
  }

  // epilogue: D row = quad*4+r, col = l15 within each 16x16 tile
  #pragma unroll
  for (int ni = 0; ni < 4; ++ni) {
    int col = nBase + wCol * 64 + ni * 16 + l15;
    float bv = FINAL ? bias[col] : 0.0f;
    #pragma unroll
    for (int mi = 0; mi < 4; ++mi) {
      int row0 = mBase + wRow * 64 + mi * 16 + quad * 4;
      #pragma unroll
      for (int r = 0; r < 4; ++r) {
        int row = row0 + r;
        if (row < N_NODES) {
          size_t idx = (size_t)row * FEAT + col;
          float v = acc[mi][ni][r];
          if (ACCUM) v += C[idx];
          if (FINAL) { v += bv; v = fmaxf(v, 0.0f); }
          C[idx] = v;
        }
      }
    }
  }
}

extern "C" void kernel_launch(void* const* d_in, const int* in_sizes, int n_in,
                              void* d_out, int out_size, void* d_ws, size_t ws_size,
                              hipStream_t stream) {
  const float* x    = (const float*)d_in[0];
  const float* w    = (const float*)d_in[1];
  const float* lw   = (const float*)d_in[2];
  const float* bias = (const float*)d_in[3];
  const int*   src  = (const int*)d_in[4];
  const int*   dst  = (const int*)d_in[5];
  float* out = (float*)d_out;

  char* ws = (char*)d_ws;
  const size_t SLAB  = (size_t)N_NODES * FEAT;              // elems per slab
  const size_t slabB = SLAB * 2;                            // 30.72 MB
  const size_t wtB   = (size_t)FEAT * KTOT * 2;             // 4.72 MB
  const size_t cntB  = (size_t)N_REL * N_NODES * 4;         // 0.96 MB
  const size_t slotB = (size_t)N_REL * N_NODES * CAP * 2;   // 15.36 MB (u16)
  const size_t fixedB = wtB + cntB + slotB;                 // 21.04 MB

  __bf16*         Wt     = (__bf16*)ws;
  int*            cnt    = (int*)(ws + wtB);
  unsigned short* slots  = (unsigned short*)(ws + wtB + cntB);
  __bf16*         slabs  = (__bf16*)(ws + fixedB);          // 16B-aligned

  int nSlab = (int)((ws_size - fixedB) / slabB);            // total slots incl. x slot
  if (nSlab > 9) nSlab = 9;
  int g = nSlab - 1;                                        // agg slabs per GEMM pass
  if (g > 8) g = 8;
  if (g < 1) g = 1;
  __bf16* xbf = slabs + (size_t)g * SLAB;                   // last slot = x (bf16)

  hipMemsetAsync(cnt, 0, cntB, stream);
  k_prep<<<CONV_BLOCKS + TR_BLOCKS + CNT_BLOCKS, 256, 0, stream>>>(
      x, w, lw, src, dst, xbf, Wt, cnt, slots);

  const int nMtiles  = (N_NODES + 127) / 128;               // 235
  const int gemmGrid = ((nMtiles + 7) / 8) * 32;            // 30 panels x 32 = 960

  if (g == 8) {
    // single fused GEMM: agg slabs 0..7, x at slot 8 (contiguous) -> K = 4608
    k_aggregate<<<(N_REL * N_NODES) / 4, 256, 0, stream>>>(xbf, cnt, slots, slabs,
                                                           N_REL * N_NODES);
    k_gemm<false, true><<<gemmGrid, 256, 0, stream>>>(slabs, SLAB, Wt, KTOT,
                                                      KTOT / 64, bias, out);
  } else {
    for (int r0 = 0; r0 < N_REL; r0 += g) {
      int gc2 = (N_REL - r0) < g ? (N_REL - r0) : g;
      k_aggregate<<<(gc2 * N_NODES) / 4, 256, 0, stream>>>(
          xbf, cnt + r0 * N_NODES, slots + (size_t)r0 * N_NODES * CAP,
          slabs, gc2 * N_NODES);
      if (r0 == 0)
        k_gemm<false, false><<<gemmGrid, 256, 0, stream>>>(
            slabs, SLAB, Wt + r0 * 512, KTOT, gc2 * 8, bias, out);
      else
        k_gemm<true, false><<<gemmGrid, 256, 0, stream>>>(
            slabs, SLAB, Wt + r0 * 512, KTOT, gc2 * 8, bias, out);
    }
    k_gemm<true, true><<<gemmGrid, 256, 0, stream>>>(xbf, SLAB, Wt + 4096, KTOT,
                                                     8, bias, out);
  }
}

// Round 7
// 604.748 us; speedup vs baseline: 1.0361x; 1.0133x over previous
//
#include <hip/hip_runtime.h>
#include <hip/hip_bf16.h>

#define N_NODES 30000
#define N_REL   8
#define N_EDGES 131072
#define FEAT    512
#define KTOT    4608   // 8*512 + 512
#define CAP     32

typedef __attribute__((ext_vector_type(8))) __bf16 v8bf;
typedef __attribute__((ext_vector_type(4))) __bf16 v4bf;
typedef __attribute__((ext_vector_type(4))) float  v4f;
typedef __attribute__((ext_vector_type(8))) unsigned short u16x8;

// ---------- async global->LDS (16B per lane, wave-uniform LDS base) ----------
static __device__ __forceinline__ void load_lds16(const void* g, void* l) {
  __builtin_amdgcn_global_load_lds(
      (const __attribute__((address_space(1))) void*)g,
      (__attribute__((address_space(3))) void*)l, 16, 0, 0);
}

// ---------- fused prep: convert x, transpose W, build buckets ----------
// blocks [0,15000): fp32->bf16 convert of x
// blocks [15000,17304): W transpose (144 x 16 tiles flattened)
// blocks [17304,17816): edge bucket insert, 8 edges/thread, XCD-affine:
//   count-block b handles rel (b&7); round-robin block->XCD dispatch keeps each
//   XCD's scatter inside its own rel's 1.92 MB slot region (fits 4 MB L2).
#define CONV_BLOCKS 15000
#define TR_BLOCKS   2304
#define CNT_BLOCKS  512
__global__ __launch_bounds__(256)
void k_prep(const float* __restrict__ x, const float* __restrict__ w,
            const float* __restrict__ lw, const int* __restrict__ src,
            const int* __restrict__ dst, __bf16* __restrict__ xbf,
            __bf16* __restrict__ Wt, int* __restrict__ cnt,
            unsigned short* __restrict__ slots) {
  __shared__ float t[32][33];
  const int b = blockIdx.x, tid = threadIdx.x;
  if (b < CONV_BLOCKS) {
    int i = b * 256 + tid;                          // 4 elems each
    float4 v = ((const float4*)x)[i];
    v4bf o;
    o[0] = (__bf16)v.x; o[1] = (__bf16)v.y; o[2] = (__bf16)v.z; o[3] = (__bf16)v.w;
    ((v4bf*)xbf)[i] = o;
  } else if (b < CONV_BLOCKS + TR_BLOCKS) {
    int tb = b - CONV_BLOCKS;
    int k0 = (tb % 144) * 32, n0 = (tb / 144) * 32;
    int tx = tid & 31, ty = tid >> 5;               // 32 x 8
    #pragma unroll
    for (int q = 0; q < 4; ++q) {
      int k = k0 + ty + q * 8, n = n0 + tx;
      float v = (k < 4096) ? w[(size_t)k * 512 + n] : lw[(size_t)(k - 4096) * 512 + n];
      t[ty + q * 8][tx] = v;
    }
    __syncthreads();
    #pragma unroll
    for (int q = 0; q < 4; ++q) {
      int n = n0 + ty + q * 8, k = k0 + tx;
      Wt[(size_t)n * KTOT + k] = (__bf16)t[tx][ty + q * 8];
    }
  } else {
    int cb  = b - CONV_BLOCKS - TR_BLOCKS;          // 0..511
    int rel = cb & 7;                               // XCD-affine rel
    int q   = cb >> 3;                              // 0..63 within rel
    int e0  = rel * N_EDGES + (q * 256 + tid) * 8;  // 8 edges, same rel
    int4 sa = *(const int4*)(src + e0), sb = *(const int4*)(src + e0 + 4);
    int4 da = *(const int4*)(dst + e0), db = *(const int4*)(dst + e0 + 4);
    int ss[8] = {sa.x, sa.y, sa.z, sa.w, sb.x, sb.y, sb.z, sb.w};
    int dd[8] = {da.x, da.y, da.z, da.w, db.x, db.y, db.z, db.w};
    int bb[8], pp[8];
    #pragma unroll
    for (int j = 0; j < 8; ++j) {
      bb[j] = rel * N_NODES + dd[j];
      pp[j] = atomicAdd(&cnt[bb[j]], 1);
    }
    #pragma unroll
    for (int j = 0; j < 8; ++j)
      if (pp[j] < CAP) slots[(size_t)bb[j] * CAP + pp[j]] = (unsigned short)ss[j];
  }
}

// ---------- aggregation: one wave/bucket; full-line slot prefetch + 8-deep
// wave-uniform-branch load groups ----------
__global__ __launch_bounds__(256)
void k_aggregate(const __bf16* __restrict__ xbf, const int* __restrict__ cnt,
                 const unsigned short* __restrict__ slots,
                 __bf16* __restrict__ out, int nBuckets) {
  int w = (blockIdx.x * blockDim.x + threadIdx.x) >> 6;
  int lane = threadIdx.x & 63;
  if (w >= nBuckets) return;
  const unsigned short* sl = slots + (size_t)w * CAP;
  u16x8 qs[4];                                      // one 64B line, issued up front
  qs[0] = *(const u16x8*)(sl);
  qs[1] = *(const u16x8*)(sl + 8);
  qs[2] = *(const u16x8*)(sl + 16);
  qs[3] = *(const u16x8*)(sl + 24);
  int c = cnt[w];
  int cc = c < CAP ? c : CAP;
  const __bf16* xb = xbf + (size_t)lane * 8;
  float acc[8] = {0.f,0.f,0.f,0.f,0.f,0.f,0.f,0.f};
  #pragma unroll
  for (int g = 0; g < 4; ++g) {
    if (cc > g * 8) {                               // wave-uniform branch
      int m = cc - g * 8;
      v8bf r[8];
      #pragma unroll
      for (int j = 0; j < 8; ++j)
        if (m > j) r[j] = *(const v8bf*)(xb + (size_t)qs[g][j] * FEAT);
      #pragma unroll
      for (int j = 0; j < 8; ++j)
        if (m > j) {
          #pragma unroll
          for (int t = 0; t < 8; ++t) acc[t] += (float)r[j][t];
        }
    }
  }
  float scale = 1.0f / (float)(c > 1 ? c : 1);
  v8bf o;
  #pragma unroll
  for (int t = 0; t < 8; ++t) o[t] = (__bf16)(acc[t] * scale);
  *(v8bf*)(out + (size_t)w * FEAT + lane * 8) = o;
}

// ---------- GEMM: 128x128 tile, mfma 16x16x32 bf16, XOR-swizzled LDS,
// M-ranged so a dispatch covers mtiles [mtBase, mtEnd) ----------
template <bool ACCUM, bool FINAL>
__global__ __launch_bounds__(256, 4)
void k_gemm(const __bf16* __restrict__ A, size_t slabStride,
            const __bf16* __restrict__ Wt, int wtStride, int kTiles,
            const float* __restrict__ bias, float* __restrict__ C,
            int mtBase, int mtEnd) {
  __shared__ __bf16 As[128 * 64];
  __shared__ __bf16 Bs[128 * 64];

  const int tid  = threadIdx.x;
  const int wave = tid >> 6;
  const int lane = tid & 63;
  const int lr = lane >> 3, lc = lane & 7;     // staging: row-in-chunk, 16B slot
  const int gcs = (lc ^ lr) * 8;               // swizzled global chunk (elem offset)
  const int quad = lane >> 4, l15 = lane & 15; // mfma lane decomposition
  const int wRow = wave >> 1, wCol = wave & 1;

  const int panel = blockIdx.x >> 5;
  const int w32   = blockIdx.x & 31;
  const int mtile = mtBase + panel * 8 + (w32 >> 2);
  const int ntile = w32 & 3;
  if (mtile >= mtEnd) return;                  // uniform whole-block exit
  const int mBase = mtile * 128;
  const int nBase = ntile * 128;

  v4f acc[4][4];
  #pragma unroll
  for (int i = 0; i < 4; ++i)
    #pragma unroll
    for (int j = 0; j < 4; ++j) acc[i][j] = (v4f){0.f, 0.f, 0.f, 0.f};

  for (int kt = 0; kt < kTiles; ++kt) {
    const int kk = kt * 64;
    const __bf16* aT = A + (size_t)(kk >> 9) * slabStride + (kk & 511);
    #pragma unroll
    for (int t = 0; t < 4; ++t) {
      int chunk = wave * 4 + t;                 // 8 rows x 64 cols per chunk
      int row = mBase + chunk * 8 + lr;
      if (row > N_NODES - 1) row = N_NODES - 1; // clamp; masked at store
      load_lds16(aT + (size_t)row * FEAT + gcs, As + chunk * 512);
      int n = nBase + chunk * 8 + lr;
      load_lds16(Wt + (size_t)n * wtStride + kk + gcs, Bs + chunk * 512);
    }
    __syncthreads();
    #pragma unroll
    for (int ks = 0; ks < 2; ++ks) {
      const int q = ks * 4 + quad;              // 16B chunk wanted this phase
      v8bf af[4], bfr[4];
      #pragma unroll
      for (int mi = 0; mi < 4; ++mi) {
        int m = wRow * 64 + mi * 16 + l15;
        af[mi] = *(const v8bf*)(As + m * 64 + ((q ^ (m & 7)) * 8));
      }
      #pragma unroll
      for (int ni = 0; ni < 4; ++ni) {
        int n = wCol * 64 + ni * 16 + l15;
        bfr[ni] = *(const v8bf*)(Bs + n * 64 + ((q ^ (n & 7)) * 8));
      }
      #pragma unroll
      for (int mi = 0; mi < 4; ++mi)
        #pragma unroll
        for (int ni = 0; ni < 4; ++ni)
          acc[mi][ni] = __builtin_amdgcn_mfma_f32_16x16x32_bf16(af[mi], bfr[ni], acc[mi][ni], 0, 0, 0);
    }
    __syncthreads();
  }

  // epilogue: D row = quad*4+r, col = l15 within each 16x16 tile
  #pragma unroll
  for (int ni = 0; ni < 4; ++ni) {
    int col = nBase + wCol * 64 + ni * 16 + l15;
    float bv = FINAL ? bias[col] : 0.0f;
    #pragma unroll
    for (int mi = 0; mi < 4; ++mi) {
      int row0 = mBase + wRow * 64 + mi * 16 + quad * 4;
      #pragma unroll
      for (int r = 0; r < 4; ++r) {
        int row = row0 + r;
        if (row < N_NODES) {
          size_t idx = (size_t)row * FEAT + col;
          float v = acc[mi][ni][r];
          if (ACCUM) v += C[idx];
          if (FINAL) { v += bv; v = fmaxf(v, 0.0f); }
          C[idx] = v;
        }
      }
    }
  }
}

extern "C" void kernel_launch(void* const* d_in, const int* in_sizes, int n_in,
                              void* d_out, int out_size, void* d_ws, size_t ws_size,
                              hipStream_t stream) {
  const float* x    = (const float*)d_in[0];
  const float* w    = (const float*)d_in[1];
  const float* lw   = (const float*)d_in[2];
  const float* bias = (const float*)d_in[3];
  const int*   src  = (const int*)d_in[4];
  const int*   dst  = (const int*)d_in[5];
  float* out = (float*)d_out;

  char* ws = (char*)d_ws;
  const size_t SLAB  = (size_t)N_NODES * FEAT;              // elems per slab
  const size_t slabB = SLAB * 2;                            // 30.72 MB
  const size_t wtB   = (size_t)FEAT * KTOT * 2;             // 4.72 MB
  const size_t cntB  = (size_t)N_REL * N_NODES * 4;         // 0.96 MB
  const size_t slotB = (size_t)N_REL * N_NODES * CAP * 2;   // 15.36 MB (u16)
  const size_t fixedB = wtB + cntB + slotB;                 // 21.04 MB

  __bf16*         Wt     = (__bf16*)ws;
  int*            cnt    = (int*)(ws + wtB);
  unsigned short* slots  = (unsigned short*)(ws + wtB + cntB);
  __bf16*         slabs  = (__bf16*)(ws + fixedB);          // 16B-aligned

  int nSlab = (int)((ws_size - fixedB) / slabB);            // total slots incl. x slot
  if (nSlab > 9) nSlab = 9;
  int g = nSlab - 1;                                        // agg slabs per GEMM pass
  if (g > 8) g = 8;
  if (g < 1) g = 1;
  __bf16* xbf = slabs + (size_t)g * SLAB;                   // last slot = x (bf16)

  hipMemsetAsync(cnt, 0, cntB, stream);
  k_prep<<<CONV_BLOCKS + TR_BLOCKS + CNT_BLOCKS, 256, 0, stream>>>(
      x, w, lw, src, dst, xbf, Wt, cnt, slots);

  const int nMtiles = (N_NODES + 127) / 128;                // 235

  if (g == 8) {
    // single fused GEMM problem: agg slabs 0..7, x at slot 8 -> K = 4608,
    // dispatched as 2 M-halves; aggregate as 2 bucket-halves (diagnostic splits).
    const int hB = (N_REL * N_NODES) / 2;                   // 120000 buckets each
    k_aggregate<<<hB / 4, 256, 0, stream>>>(xbf, cnt, slots, slabs, hB);
    k_aggregate<<<hB / 4, 256, 0, stream>>>(xbf, cnt + hB,
                                            slots + (size_t)hB * CAP,
                                            slabs + (size_t)hB * FEAT, hB);
    const int mtMid = nMtiles / 2;                          // 117
    const int grid1 = ((mtMid + 7) / 8) * 32;               // 15 panels
    const int grid2 = ((nMtiles - mtMid + 7) / 8) * 32;     // 15 panels
    k_gemm<false, true><<<grid1, 256, 0, stream>>>(slabs, SLAB, Wt, KTOT,
                                                   KTOT / 64, bias, out, 0, mtMid);
    k_gemm<false, true><<<grid2, 256, 0, stream>>>(slabs, SLAB, Wt, KTOT,
                                                   KTOT / 64, bias, out, mtMid, nMtiles);
  } else {
    const int gemmGrid = ((nMtiles + 7) / 8) * 32;
    for (int r0 = 0; r0 < N_REL; r0 += g) {
      int gc2 = (N_REL - r0) < g ? (N_REL - r0) : g;
      k_aggregate<<<(gc2 * N_NODES) / 4, 256, 0, stream>>>(
          xbf, cnt + r0 * N_NODES, slots + (size_t)r0 * N_NODES * CAP,
          slabs, gc2 * N_NODES);
      if (r0 == 0)
        k_gemm<false, false><<<gemmGrid, 256, 0, stream>>>(
            slabs, SLAB, Wt + r0 * 512, KTOT, gc2 * 8, bias, out, 0, nMtiles);
      else
        k_gemm<true, false><<<gemmGrid, 256, 0, stream>>>(
            slabs, SLAB, Wt + r0 * 512, KTOT, gc2 * 8, bias, out, 0, nMtiles);
    }
    k_gemm<true, true><<<gemmGrid, 256, 0, stream>>>(xbf, SLAB, Wt + 4096, KTOT,
                                                     8, bias, out, 0, nMtiles);
  }
}